// Round 21
// baseline (92.640 us; speedup 1.0000x reference)
//
#include <hip/hip_runtime.h>

#define T_DIM 8192
#define N_DIM 8
#define C_DIM 64
#define KB    2048
#define NT    (N_DIM * T_DIM)        // 65536 rows
#define TOTX  ((size_t)NT * C_DIM)   // 4194304 elements
#define NBLK  2048                   // argmin blocks (32 rows each)
#define LISTCAP 65536
#define TAU   0.045f

// Scratch offsets in FLOAT units from scratch base (d_ws if big enough,
// else out + NT with the fallback xd_kernel path).
#define SCR_COUNT 0                   // int
#define SCR_LIST  16                  // int[65536]      -> ends 65552
#define SCR_PART  65792               // float[2048][8]  -> ends 82176
#define SCR_KK    82432               // float[2048]     -> ends 84480
#define SCR_K     90112               // f16x8 k9[16][9][128] (288 KB) -> 163840
#define SCR_FIX   262144              // float[65536][16] (4 MB) -> ends 1310720
#define WS_NEED_BYTES ((size_t)1310720 * 4)

typedef _Float16 half_t;
typedef _Float16 f16x8 __attribute__((ext_vector_type(8)));
typedef float    f32x16 __attribute__((ext_vector_type(16)));

// numpy pairwise sum (n=64) of squares (np-exact, fixup path).
__device__ __forceinline__ float np_sumsq64(const float* __restrict__ a) {
    float r[8];
    #pragma unroll
    for (int j = 0; j < 8; ++j) r[j] = __fmul_rn(a[j], a[j]);
    #pragma unroll
    for (int i = 8; i < 64; i += 8)
        #pragma unroll
        for (int j = 0; j < 8; ++j)
            r[j] = __fadd_rn(r[j], __fmul_rn(a[i + j], a[i + j]));
    return __fadd_rn(__fadd_rn(__fadd_rn(r[0], r[1]), __fadd_rn(r[2], r[3])),
                     __fadd_rn(__fadd_rn(r[4], r[5]), __fadd_rn(r[6], r[7])));
}

// ------------------------------------------------------------------ k prep ----
__global__ __launch_bounds__(64) void kprep_kernel(const float* __restrict__ k,
                                                   float* __restrict__ base) {
    const int bin = blockIdx.x * 64 + threadIdx.x;    // grid 32 -> 2048
    if (bin == 0) ((int*)base)[SCR_COUNT] = 0;

    float kv[64];
    #pragma unroll
    for (int i = 0; i < 16; ++i)
        *(float4*)&kv[i * 4] = *(const float4*)(k + (size_t)bin * 64 + i * 4);

    float kn = 0.f;
    #pragma unroll
    for (int c = 0; c < 64; ++c) kn = fmaf(kv[c], kv[c], kn);
    base[SCR_KK + bin] = np_sumsq64(kv);

    f16x8* kscr = (f16x8*)(base + SCR_K);
    const int ch = bin >> 7, b127 = bin & 127;
    #pragma unroll
    for (int slot = 0; slot < 8; ++slot) {
        f16x8 h8;
        #pragma unroll
        for (int e = 0; e < 8; ++e)
            h8[e] = (half_t)(-2.f * (float)((half_t)kv[slot * 8 + e]));
        kscr[(size_t)ch * 1152 + slot * 128 + b127] = h8;
    }
    {
        half_t knh = (half_t)kn;
        half_t knl = (half_t)(kn - (float)knh);
        f16x8 k8;
        #pragma unroll
        for (int e = 0; e < 8; ++e) k8[e] = (half_t)0.f;
        k8[0] = knh; k8[1] = knl;
        kscr[(size_t)ch * 1152 + 1024 + b127] = k8;
    }
}

// ------------------------------------------------------------------ argmin ----
// Grid 2048, block = 32 rows x 4 waves: wave w owns bins [w*512,(w+1)*512).
// BINS-AS-M, 6-bit packed keys (tile<<2 | rlow in the score's low mantissa):
// UPD = and_or + med3 + min (3 VALU, no index registers).
// WSMODE=1: also writes x_d inline (scratch lives in d_ws).
template <int WSMODE>
__global__ __launch_bounds__(256, 2) void argmin_kernel(const float* __restrict__ x,
                                                        const float* __restrict__ mask,
                                                        const float* __restrict__ k,
                                                        float* __restrict__ out,
                                                        float* __restrict__ base) {
    __shared__ __align__(16) f16x8 xhi_s[256];   // [8 slots][32 rows]
    __shared__ float psx[8][32], psxx[8][32];
    __shared__ float wres[4][32][3];
    __shared__ int   sbest_s[32];

    const int tid = threadIdx.x;
    const int l   = tid & 63, w = tid >> 6;
    const int col = l & 31, kg = l >> 5;
    const int r0  = blockIdx.x * 32;
    const int n   = r0 >> 13;
    const int t0  = r0 & (T_DIM - 1);

    // prologue: x load + f16-hi split + row stats (thread: row=tid&31, 1 slot)
    {
        const int row = tid & 31, slot = tid >> 5;
        float sx = 0.f, sxx = 0.f;
        f16x8 h8;
        #pragma unroll
        for (int e = 0; e < 8; ++e) {
            float v = x[((size_t)n * C_DIM + slot * 8 + e) * T_DIM + t0 + row];
            h8[e] = (half_t)v;
            sx += v; sxx = fmaf(v, v, sxx);
        }
        xhi_s[slot * 32 + row] = h8;
        psx[slot][row]  = sx;
        psxx[slot][row] = sxx;
    }
    __syncthreads();

    // x B-fragments: col = x-row, K=64 over 4 k-steps + ones frag
    f16x8 a0 = xhi_s[(0 + kg) * 32 + col];
    f16x8 a1 = xhi_s[(2 + kg) * 32 + col];
    f16x8 a2 = xhi_s[(4 + kg) * 32 + col];
    f16x8 a3 = xhi_s[(6 + kg) * 32 + col];
    f16x8 aones;
    #pragma unroll
    for (int e = 0; e < 8; ++e) aones[e] = (half_t)0.f;
    if (kg == 0) { aones[0] = (half_t)1.f; aones[1] = (half_t)1.f; }

    // per-wave k base: bins [w*512, (w+1)*512) = chunks w*4 .. w*4+3
    const f16x8* kf0 = (const f16x8*)(base + SCR_K) + (size_t)w * 4 * 1152 + col;
    const int kgo = kg * 128;

    f32x16 zacc;
    #pragma unroll
    for (int r = 0; r < 16; ++r) zacc[r] = 0.f;

    // 4 independent top-2 packed chains: chain j handles acc entries 4j..4j+3
    float bv0 = __builtin_inff(), b20 = __builtin_inff();
    float bv1 = __builtin_inff(), b21 = __builtin_inff();
    float bv2 = __builtin_inff(), b22 = __builtin_inff();
    float bv3 = __builtin_inff(), b23 = __builtin_inff();

    f16x8 bA[4], bB[4], b4A, b4B;

#define LOADT(t, BH, B4)                                            \
    {                                                               \
        const f16x8* p = kf0 + (((t) >> 2) * 1152 + ((t) & 3) * 32);\
        BH[0] = p[kgo]; BH[1] = p[kgo + 256];                       \
        BH[2] = p[kgo + 512]; BH[3] = p[kgo + 768];                 \
        B4 = p[1024];                                               \
    }

#define UPD(J, RR, CODE)                                                     \
    {                                                                        \
        float spf = __uint_as_float(                                         \
            (__float_as_uint(acc[RR]) & 0xFFFFFFC0u) | (unsigned)(CODE));    \
        float nb2;                                                           \
        asm("v_med3_f32 %0, %1, %2, %3"                                      \
            : "=v"(nb2) : "v"(spf), "v"(bv##J), "v"(b2##J));                 \
        b2##J = nb2;                                                         \
        bv##J = fminf(bv##J, spf);                                           \
    }

#define COMPT(t, BH, B4)                                                     \
    {                                                                        \
        f32x16 acc = __builtin_amdgcn_mfma_f32_32x32x16_f16(B4, aones, zacc, 0, 0, 0); \
        acc = __builtin_amdgcn_mfma_f32_32x32x16_f16(BH[0], a0, acc, 0, 0, 0); \
        acc = __builtin_amdgcn_mfma_f32_32x32x16_f16(BH[1], a1, acc, 0, 0, 0); \
        acc = __builtin_amdgcn_mfma_f32_32x32x16_f16(BH[2], a2, acc, 0, 0, 0); \
        acc = __builtin_amdgcn_mfma_f32_32x32x16_f16(BH[3], a3, acc, 0, 0, 0); \
        const int cb4 = (t) * 4;                                             \
        UPD(0, 0, cb4 + 0)  UPD(0, 1, cb4 + 1)  UPD(0, 2, cb4 + 2)  UPD(0, 3, cb4 + 3) \
        UPD(1, 4, cb4 + 0)  UPD(1, 5, cb4 + 1)  UPD(1, 6, cb4 + 2)  UPD(1, 7, cb4 + 3) \
        UPD(2, 8, cb4 + 0)  UPD(2, 9, cb4 + 1)  UPD(2, 10, cb4 + 2) UPD(2, 11, cb4 + 3) \
        UPD(3, 12, cb4 + 0) UPD(3, 13, cb4 + 1) UPD(3, 14, cb4 + 2) UPD(3, 15, cb4 + 3) \
    }

    LOADT(0, bA, b4A);
    #pragma unroll 1
    for (int t = 0; t < 14; t += 2) {
        LOADT(t + 1, bB, b4B);
        COMPT(t, bA, b4A);
        LOADT(t + 2, bA, b4A);
        COMPT(t + 1, bB, b4B);
    }
    LOADT(15, bB, b4B);
    COMPT(14, bA, b4A);
    COMPT(15, bB, b4B);
#undef LOADT
#undef COMPT
#undef UPD

    // reconstruct (value, bin) per chain:
    // bin = w*512 + (code>>2)*32 + 8*j + (code&3) + 4*kg
    const int bbase = w * 512 + 4 * kg;
    int c0, c1, c2, c3;
    {
        unsigned q;
        q = __float_as_uint(bv0) & 63u; c0 = bbase + (int)(q >> 2) * 32 + 0  + (int)(q & 3);
        q = __float_as_uint(bv1) & 63u; c1 = bbase + (int)(q >> 2) * 32 + 8  + (int)(q & 3);
        q = __float_as_uint(bv2) & 63u; c2 = bbase + (int)(q >> 2) * 32 + 16 + (int)(q & 3);
        q = __float_as_uint(bv3) & 63u; c3 = bbase + (int)(q >> 2) * 32 + 24 + (int)(q & 3);
    }

    // merge 4 chains -> (bv, b2, bb)   [top-2 merge, tie -> lower bin]
    float bv, b2; int bb;
    {
        float m01v; int m01c; float m01s;
        if (bv1 < bv0 || (bv1 == bv0 && c1 < c0)) { m01v = bv1; m01c = c1; }
        else                                      { m01v = bv0; m01c = c0; }
        m01s = fminf(fminf(b20, b21), fmaxf(bv0, bv1));
        float m23v; int m23c; float m23s;
        if (bv3 < bv2 || (bv3 == bv2 && c3 < c2)) { m23v = bv3; m23c = c3; }
        else                                      { m23v = bv2; m23c = c2; }
        m23s = fminf(fminf(b22, b23), fmaxf(bv2, bv3));
        if (m23v < m01v || (m23v == m01v && m23c < m01c)) { bv = m23v; bb = m23c; }
        else                                              { bv = m01v; bb = m01c; }
        b2 = fminf(fminf(m01s, m23s), fmaxf(m01v, m23v));
    }

    // single-stage lane^32 merge (two bin-subsets of the same x-row)
    {
        float ov = __shfl_xor(bv, 32, 64);
        float o2 = __shfl_xor(b2, 32, 64);
        int   ob = __shfl_xor(bb, 32, 64);
        b2 = fminf(fminf(b2, o2), fmaxf(bv, ov));
        if (ov < bv || (ov == bv && ob < bb)) { bv = ov; bb = ob; }
    }

    // lanes 0..31 hold final per-row results for this bin quarter
    if (kg == 0) {
        wres[w][col][0] = bv;
        wres[w][col][1] = b2;
        wres[w][col][2] = __int_as_float(bb);
    }
    __syncthreads();

    // final merge: threads 0..31 (wave 0) own one row each
    if (tid < 32) {
        const int row = tid;
        const float v0 = wres[0][row][0], v1 = wres[1][row][0];
        const float v2 = wres[2][row][0], v3 = wres[3][row][0];
        float fbv = v0; int fbb = __float_as_int(wres[0][row][2]);
        if (v1 < fbv) { fbv = v1; fbb = __float_as_int(wres[1][row][2]); }
        if (v2 < fbv) { fbv = v2; fbb = __float_as_int(wres[2][row][2]); }
        if (v3 < fbv) { fbv = v3; fbb = __float_as_int(wres[3][row][2]); }
        const float m01 = fminf(v0, v1), M01 = fmaxf(v0, v1);
        const float m23 = fminf(v2, v3), M23 = fmaxf(v2, v3);
        const float sec = fminf(fmaxf(m01, m23), fminf(M01, M23));
        const float fb2 = fminf(sec,
            fminf(fminf(wres[0][row][1], wres[1][row][1]),
                  fminf(wres[2][row][1], wres[3][row][1])));

        out[r0 + row] = (float)fbb;
        sbest_s[row] = fbb;
        if (fb2 - fbv < TAU) {
            int idx = atomicAdd((int*)base + SCR_COUNT, 1);
            if (idx < LISTCAP) ((int*)base + SCR_LIST)[idx] = r0 + row;
        }
        float sx = 0.f, sxx = 0.f;
        #pragma unroll
        for (int sp = 0; sp < 8; ++sp) { sx += psx[sp][row]; sxx += psxx[sp][row]; }
        const float m  = mask[r0 + row];
        const float d2 = sxx + fbv;
        float vals[5] = { m * d2, d2, m, sx, sxx };
        #pragma unroll
        for (int off = 1; off <= 16; off <<= 1)
            #pragma unroll
            for (int q = 0; q < 5; ++q) vals[q] += __shfl_xor(vals[q], off, 64);
        if (tid == 0) {
            float* partials = base + SCR_PART;
            #pragma unroll
            for (int q = 0; q < 5; ++q)
                partials[(size_t)blockIdx.x * 8 + q] = vals[q];
        }
    }

    if (WSMODE) {
        __syncthreads();
        // x_d inline write (scratch is in d_ws, so out+NT is free)
        const int row = tid & 31, slot = tid >> 5;
        const int b = sbest_s[row];
        const float m = mask[r0 + row];
        float* xd = out + NT;
        #pragma unroll
        for (int e = 0; e < 8; ++e)
            xd[((size_t)n * C_DIM + slot * 8 + e) * T_DIM + t0 + row] =
                k[(size_t)b * C_DIM + slot * 8 + e] * m;
    }
}

// ------------------------------------------------------------------ fixup ----
// Work unit = (32-row batch) x (256-bin chunk); np-f32-exact partials -> SCR_FIX.
__global__ __launch_bounds__(256) void fixup_kernel(const float* __restrict__ x,
                                                    const float* __restrict__ k,
                                                    float* __restrict__ base) {
    __shared__ float xs[32][65];
    __shared__ float sxx_s[32];
    __shared__ float redv[256];
    __shared__ int   redb[256];

    const int tid = threadIdx.x;
    const int* count    = (const int*)base + SCR_COUNT;
    const int* flaglist = (const int*)base + SCR_LIST;
    const float* kk     = base + SCR_KK;
    float* fix          = base + SCR_FIX;
    int cnt = *count;
    if (cnt > LISTCAP) cnt = LISTCAP;
    const int nb8 = ((cnt + 31) >> 5) << 3;

    const int rloc = tid & 31, part = tid >> 5;

    for (int wk = blockIdx.x; wk < nb8; wk += gridDim.x) {
        const int bi = wk >> 3, chunk = wk & 7;
        int li = bi * 32 + rloc;
        if (li >= cnt) li = bi * 32;                 // clamp (duplicate row ok)
        const int row = flaglist[li];
        const int n = row >> 13, t = row & (T_DIM - 1);
        #pragma unroll
        for (int e = 0; e < 8; ++e)
            xs[rloc][part * 8 + e] = x[((size_t)n * C_DIM + part * 8 + e) * T_DIM + t];
        __syncthreads();
        if (tid < 32) sxx_s[tid] = np_sumsq64(&xs[tid][0]);
        __syncthreads();

        float xr[64];
        #pragma unroll
        for (int c = 0; c < 64; ++c) xr[c] = xs[rloc][c];
        const float xx = sxx_s[rloc];

        float bv = __builtin_inff();
        int   bb = 0x7fffffff;
        const int bbase = chunk * 256 + part * 32;
        #pragma unroll 1
        for (int i = 0; i < 32; i += 2) {
            const int b0 = bbase + i;
            const int b1 = b0 + 1;
            const float* k0 = k + (size_t)b0 * 64;
            const float* k1 = k + (size_t)b1 * 64;
            float d0 = 0.f, d1 = 0.f;
            #pragma unroll
            for (int c = 0; c < 64; ++c) {
                d0 = fmaf(xr[c], k0[c], d0);
                d1 = fmaf(xr[c], k1[c], d1);
            }
            float s0 = __fadd_rn(__fsub_rn(xx, __fadd_rn(d0, d0)), kk[b0]);
            float s1 = __fadd_rn(__fsub_rn(xx, __fadd_rn(d1, d1)), kk[b1]);
            if (s0 < bv || (s0 == bv && b0 < bb)) { bv = s0; bb = b0; }
            if (s1 < bv || (s1 == bv && b1 < bb)) { bv = s1; bb = b1; }
        }
        redv[tid] = bv; redb[tid] = bb;
        __syncthreads();
        if (tid < 32) {
            float fv = redv[tid]; int fb = redb[tid];
            #pragma unroll
            for (int p = 1; p < 8; ++p) {
                float ov = redv[p * 32 + tid];
                int   ob = redb[p * 32 + tid];
                if (ov < fv || (ov == fv && ob < fb)) { fv = ov; fb = ob; }
            }
            const int fi = bi * 32 + tid;
            if (fi < cnt) {
                fix[(size_t)fi * 16 + chunk * 2]     = fv;
                fix[(size_t)fi * 16 + chunk * 2 + 1] = __int_as_float(fb);
            }
        }
        __syncthreads();
    }
}

// ------------------------------------------- fixmerge + finalize (fused) ----
// WSMODE=1: also patches x_d rows for flagged rows.
template <int WSMODE>
__global__ __launch_bounds__(256) void fixmerge_kernel(const float* __restrict__ mask,
                                                       const float* __restrict__ k,
                                                       float* __restrict__ out,
                                                       float* __restrict__ base) {
    const int* count    = (const int*)base + SCR_COUNT;
    const int* flaglist = (const int*)base + SCR_LIST;
    const float* fix    = base + SCR_FIX;
    const int tid = threadIdx.x;
    int cnt = *count;
    if (cnt > LISTCAP) cnt = LISTCAP;

    for (int fi = blockIdx.x * 256 + tid; fi < cnt; fi += gridDim.x * 256) {
        const float* p = fix + (size_t)fi * 16;
        float bv = p[0];
        int   bb = __float_as_int(p[1]);
        #pragma unroll
        for (int c = 1; c < 8; ++c) {
            float v = p[c * 2];
            int   b = __float_as_int(p[c * 2 + 1]);
            if (v < bv || (v == bv && b < bb)) { bv = v; bb = b; }
        }
        const int row = flaglist[fi];
        out[row] = (float)bb;
        if (WSMODE) {
            const int n = row >> 13, t = row & (T_DIM - 1);
            const float m = mask[row];
            const float* kr = k + (size_t)bb * C_DIM;
            float* xd = out + NT;
            #pragma unroll
            for (int c = 0; c < C_DIM; ++c)
                xd[((size_t)n * C_DIM + c) * T_DIM + t] = kr[c] * m;
        }
    }

    // block 0: finalize scalars
    if (blockIdx.x == 0) {
        const float* partials = base + SCR_PART;
        double vals[5] = {0, 0, 0, 0, 0};
        for (int i = tid; i < NBLK; i += 256)
            #pragma unroll
            for (int q = 0; q < 5; ++q) vals[q] += (double)partials[(size_t)i * 8 + q];
        #pragma unroll
        for (int off = 1; off <= 32; off <<= 1)
            #pragma unroll
            for (int q = 0; q < 5; ++q) vals[q] += __shfl_xor(vals[q], off, 64);
        __shared__ double sred[4][5];
        const int wid = tid >> 6, lane = tid & 63;
        if (lane == 0)
            for (int q = 0; q < 5; ++q) sred[wid][q] = vals[q];
        __syncthreads();
        if (tid == 0) {
            double cm  = sred[0][0] + sred[1][0] + sred[2][0] + sred[3][0];
            double fs  = sred[0][1] + sred[1][1] + sred[2][1] + sred[3][1];
            double ms  = sred[0][2] + sred[1][2] + sred[2][2] + sred[3][2];
            double sx  = sred[0][3] + sred[1][3] + sred[2][3] + sred[3][3];
            double sxx = sred[0][4] + sred[1][4] + sred[2][4] + sred[3][4];
            double sz  = (double)TOTX;
            out[NT + TOTX + 0] = (float)(cm / (ms * (double)C_DIM));
            out[NT + TOTX + 1] = (float)(fs / (double)NT);
            out[NT + TOTX + 2] = (float)sqrt(fmax(0.0, (sxx - sx * sx / sz) / sz));
        }
    }
}

// --------------------------------------- x_d (fallback path only) ----
__global__ __launch_bounds__(256) void xd_kernel(const float* __restrict__ mask,
                                                 const float* __restrict__ k,
                                                 float* __restrict__ out) {
    const int row = blockIdx.x * 256 + threadIdx.x;
    const int n = row >> 13, t = row & (T_DIM - 1);
    const int b = (int)out[row];
    const float m = mask[row];
    const float* kr = k + (size_t)b * C_DIM;
    float* xd = out + NT;
    #pragma unroll
    for (int c = 0; c < C_DIM; ++c)
        xd[((size_t)n * C_DIM + c) * T_DIM + t] = kr[c] * m;
}

// ----------------------------------------------------------------- launch ----
extern "C" void kernel_launch(void* const* d_in, const int* in_sizes, int n_in,
                              void* d_out, int out_size, void* d_ws, size_t ws_size,
                              hipStream_t stream) {
    (void)in_sizes; (void)n_in; (void)out_size;
    const float* x    = (const float*)d_in[0];
    const float* mask = (const float*)d_in[1];
    const float* k    = (const float*)d_in[2];
    float* out = (float*)d_out;

    if (ws_size >= WS_NEED_BYTES) {
        float* base = (float*)d_ws;
        kprep_kernel<<<32, 64, 0, stream>>>(k, base);
        argmin_kernel<1><<<NBLK, 256, 0, stream>>>(x, mask, k, out, base);
        fixup_kernel<<<2048, 256, 0, stream>>>(x, k, base);
        fixmerge_kernel<1><<<256, 256, 0, stream>>>(mask, k, out, base);
    } else {
        float* base = out + NT;
        kprep_kernel<<<32, 64, 0, stream>>>(k, base);
        argmin_kernel<0><<<NBLK, 256, 0, stream>>>(x, mask, k, out, base);
        fixup_kernel<<<2048, 256, 0, stream>>>(x, k, base);
        fixmerge_kernel<0><<<256, 256, 0, stream>>>(mask, k, out, base);
        xd_kernel<<<NT / 256, 256, 0, stream>>>(mask, k, out);
    }
}

// Round 22
// 84.092 us; speedup vs baseline: 1.1017x; 1.1017x over previous
//
#include <hip/hip_runtime.h>

#define T_DIM 8192
#define N_DIM 8
#define C_DIM 64
#define KB    2048
#define NT    (N_DIM * T_DIM)        // 65536 rows
#define TOTX  ((size_t)NT * C_DIM)   // 4194304 elements
#define NBLK  2048                   // argmin blocks (32 rows each)
#define LISTCAP 65536
#define TAU   0.045f

// Scratch offsets in FLOAT units from scratch base (d_ws if big enough,
// else out + NT; xd_kernel runs LAST and overwrites the out-region scratch).
#define SCR_COUNT 0                   // int
#define SCR_LIST  16                  // int[65536]      -> ends 65552
#define SCR_PART  65792               // float[2048][8]  -> ends 82176
#define SCR_KK    82432               // float[2048]     -> ends 84480
#define SCR_K     90112               // f16x8 k9[16][9][128] (288 KB) -> 163840
#define SCR_FIX   262144              // float[65536][16] (4 MB) -> ends 1310720
#define WS_NEED_BYTES ((size_t)1310720 * 4)

typedef _Float16 half_t;
typedef _Float16 f16x8 __attribute__((ext_vector_type(8)));
typedef float    f32x16 __attribute__((ext_vector_type(16)));

// numpy pairwise sum (n=64) of squares (np-exact, fixup path).
__device__ __forceinline__ float np_sumsq64(const float* __restrict__ a) {
    float r[8];
    #pragma unroll
    for (int j = 0; j < 8; ++j) r[j] = __fmul_rn(a[j], a[j]);
    #pragma unroll
    for (int i = 8; i < 64; i += 8)
        #pragma unroll
        for (int j = 0; j < 8; ++j)
            r[j] = __fadd_rn(r[j], __fmul_rn(a[i + j], a[i + j]));
    return __fadd_rn(__fadd_rn(__fadd_rn(r[0], r[1]), __fadd_rn(r[2], r[3])),
                     __fadd_rn(__fadd_rn(r[4], r[5]), __fadd_rn(r[6], r[7])));
}

// ------------------------------------------------------------------ k prep ----
__global__ __launch_bounds__(64) void kprep_kernel(const float* __restrict__ k,
                                                   float* __restrict__ base) {
    const int bin = blockIdx.x * 64 + threadIdx.x;    // grid 32 -> 2048
    if (bin == 0) ((int*)base)[SCR_COUNT] = 0;

    float kv[64];
    #pragma unroll
    for (int i = 0; i < 16; ++i)
        *(float4*)&kv[i * 4] = *(const float4*)(k + (size_t)bin * 64 + i * 4);

    float kn = 0.f;
    #pragma unroll
    for (int c = 0; c < 64; ++c) kn = fmaf(kv[c], kv[c], kn);
    base[SCR_KK + bin] = np_sumsq64(kv);

    f16x8* kscr = (f16x8*)(base + SCR_K);
    const int ch = bin >> 7, b127 = bin & 127;
    #pragma unroll
    for (int slot = 0; slot < 8; ++slot) {
        f16x8 h8;
        #pragma unroll
        for (int e = 0; e < 8; ++e)
            h8[e] = (half_t)(-2.f * (float)((half_t)kv[slot * 8 + e]));
        kscr[(size_t)ch * 1152 + slot * 128 + b127] = h8;
    }
    {
        half_t knh = (half_t)kn;
        half_t knl = (half_t)(kn - (float)knh);
        f16x8 k8;
        #pragma unroll
        for (int e = 0; e < 8; ++e) k8[e] = (half_t)0.f;
        k8[0] = knh; k8[1] = knl;
        kscr[(size_t)ch * 1152 + 1024 + b127] = k8;
    }
}

// ------------------------------------------------------------------ argmin ----
// Grid 2048, block = 32 rows x 4 waves: wave w owns bins [w*512,(w+1)*512).
// BINS-AS-M, 6-bit packed keys, 4 rotating reg buffers (distance-2 prefetch).
__global__ __launch_bounds__(256, 2) void argmin_kernel(const float* __restrict__ x,
                                                        const float* __restrict__ mask,
                                                        float* __restrict__ out,
                                                        float* __restrict__ base) {
    __shared__ __align__(16) f16x8 xhi_s[256];   // [8 slots][32 rows]
    __shared__ float psx[8][32], psxx[8][32];
    __shared__ float wres[4][32][3];

    const int tid = threadIdx.x;
    const int l   = tid & 63, w = tid >> 6;
    const int col = l & 31, kg = l >> 5;
    const int r0  = blockIdx.x * 32;
    const int n   = r0 >> 13;
    const int t0  = r0 & (T_DIM - 1);

    // prologue: x load + f16-hi split + row stats (thread: row=tid&31, 1 slot)
    {
        const int row = tid & 31, slot = tid >> 5;
        float sx = 0.f, sxx = 0.f;
        f16x8 h8;
        #pragma unroll
        for (int e = 0; e < 8; ++e) {
            float v = x[((size_t)n * C_DIM + slot * 8 + e) * T_DIM + t0 + row];
            h8[e] = (half_t)v;
            sx += v; sxx = fmaf(v, v, sxx);
        }
        xhi_s[slot * 32 + row] = h8;
        psx[slot][row]  = sx;
        psxx[slot][row] = sxx;
    }
    __syncthreads();

    // x B-fragments: col = x-row, K=64 over 4 k-steps + ones frag
    f16x8 a0 = xhi_s[(0 + kg) * 32 + col];
    f16x8 a1 = xhi_s[(2 + kg) * 32 + col];
    f16x8 a2 = xhi_s[(4 + kg) * 32 + col];
    f16x8 a3 = xhi_s[(6 + kg) * 32 + col];
    f16x8 aones;
    #pragma unroll
    for (int e = 0; e < 8; ++e) aones[e] = (half_t)0.f;
    if (kg == 0) { aones[0] = (half_t)1.f; aones[1] = (half_t)1.f; }

    // per-wave k base: bins [w*512, (w+1)*512) = chunks w*4 .. w*4+3
    const f16x8* kf0 = (const f16x8*)(base + SCR_K) + (size_t)w * 4 * 1152 + col;
    const int kgo = kg * 128;

    f32x16 zacc;
    #pragma unroll
    for (int r = 0; r < 16; ++r) zacc[r] = 0.f;

    // 4 independent top-2 packed chains: chain j handles acc entries 4j..4j+3
    float bv0 = __builtin_inff(), b20 = __builtin_inff();
    float bv1 = __builtin_inff(), b21 = __builtin_inff();
    float bv2 = __builtin_inff(), b22 = __builtin_inff();
    float bv3 = __builtin_inff(), b23 = __builtin_inff();

    f16x8 bA[4], bB[4], bC[4], bD[4], b4A, b4B, b4C, b4D;

#define LOADT(t, BH, B4)                                            \
    {                                                               \
        const f16x8* p = kf0 + (((t) >> 2) * 1152 + ((t) & 3) * 32);\
        BH[0] = p[kgo]; BH[1] = p[kgo + 256];                       \
        BH[2] = p[kgo + 512]; BH[3] = p[kgo + 768];                 \
        B4 = p[1024];                                               \
    }

#define UPD(J, RR, CODE)                                                     \
    {                                                                        \
        float spf = __uint_as_float(                                         \
            (__float_as_uint(acc[RR]) & 0xFFFFFFC0u) | (unsigned)(CODE));    \
        float nb2;                                                           \
        asm("v_med3_f32 %0, %1, %2, %3"                                      \
            : "=v"(nb2) : "v"(spf), "v"(bv##J), "v"(b2##J));                 \
        b2##J = nb2;                                                         \
        bv##J = fminf(bv##J, spf);                                           \
    }

#define COMPT(t, BH, B4)                                                     \
    {                                                                        \
        f32x16 acc = __builtin_amdgcn_mfma_f32_32x32x16_f16(B4, aones, zacc, 0, 0, 0); \
        acc = __builtin_amdgcn_mfma_f32_32x32x16_f16(BH[0], a0, acc, 0, 0, 0); \
        acc = __builtin_amdgcn_mfma_f32_32x32x16_f16(BH[1], a1, acc, 0, 0, 0); \
        acc = __builtin_amdgcn_mfma_f32_32x32x16_f16(BH[2], a2, acc, 0, 0, 0); \
        acc = __builtin_amdgcn_mfma_f32_32x32x16_f16(BH[3], a3, acc, 0, 0, 0); \
        const int cb4 = (t) * 4;                                             \
        UPD(0, 0, cb4 + 0)  UPD(0, 1, cb4 + 1)  UPD(0, 2, cb4 + 2)  UPD(0, 3, cb4 + 3) \
        UPD(1, 4, cb4 + 0)  UPD(1, 5, cb4 + 1)  UPD(1, 6, cb4 + 2)  UPD(1, 7, cb4 + 3) \
        UPD(2, 8, cb4 + 0)  UPD(2, 9, cb4 + 1)  UPD(2, 10, cb4 + 2) UPD(2, 11, cb4 + 3) \
        UPD(3, 12, cb4 + 0) UPD(3, 13, cb4 + 1) UPD(3, 14, cb4 + 2) UPD(3, 15, cb4 + 3) \
    }

    LOADT(0, bA, b4A); LOADT(1, bB, b4B);
    #pragma unroll 1
    for (int t = 0; t < 12; t += 4) {
        LOADT(t + 2, bC, b4C); COMPT(t,     bA, b4A);
        LOADT(t + 3, bD, b4D); COMPT(t + 1, bB, b4B);
        LOADT(t + 4, bA, b4A); COMPT(t + 2, bC, b4C);
        LOADT(t + 5, bB, b4B); COMPT(t + 3, bD, b4D);
    }
    LOADT(14, bC, b4C); COMPT(12, bA, b4A);
    LOADT(15, bD, b4D); COMPT(13, bB, b4B);
    COMPT(14, bC, b4C);
    COMPT(15, bD, b4D);
#undef LOADT
#undef COMPT
#undef UPD

    // reconstruct (value, bin) per chain:
    // bin = w*512 + (code>>2)*32 + 8*j + (code&3) + 4*kg
    const int bbase = w * 512 + 4 * kg;
    int c0, c1, c2, c3;
    {
        unsigned q;
        q = __float_as_uint(bv0) & 63u; c0 = bbase + (int)(q >> 2) * 32 + 0  + (int)(q & 3);
        q = __float_as_uint(bv1) & 63u; c1 = bbase + (int)(q >> 2) * 32 + 8  + (int)(q & 3);
        q = __float_as_uint(bv2) & 63u; c2 = bbase + (int)(q >> 2) * 32 + 16 + (int)(q & 3);
        q = __float_as_uint(bv3) & 63u; c3 = bbase + (int)(q >> 2) * 32 + 24 + (int)(q & 3);
    }

    // merge 4 chains -> (bv, b2, bb)   [top-2 merge, tie -> lower bin]
    float bv, b2; int bb;
    {
        float m01v; int m01c; float m01s;
        if (bv1 < bv0 || (bv1 == bv0 && c1 < c0)) { m01v = bv1; m01c = c1; }
        else                                      { m01v = bv0; m01c = c0; }
        m01s = fminf(fminf(b20, b21), fmaxf(bv0, bv1));
        float m23v; int m23c; float m23s;
        if (bv3 < bv2 || (bv3 == bv2 && c3 < c2)) { m23v = bv3; m23c = c3; }
        else                                      { m23v = bv2; m23c = c2; }
        m23s = fminf(fminf(b22, b23), fmaxf(bv2, bv3));
        if (m23v < m01v || (m23v == m01v && m23c < m01c)) { bv = m23v; bb = m23c; }
        else                                              { bv = m01v; bb = m01c; }
        b2 = fminf(fminf(m01s, m23s), fmaxf(m01v, m23v));
    }

    // single-stage lane^32 merge (two bin-subsets of the same x-row)
    {
        float ov = __shfl_xor(bv, 32, 64);
        float o2 = __shfl_xor(b2, 32, 64);
        int   ob = __shfl_xor(bb, 32, 64);
        b2 = fminf(fminf(b2, o2), fmaxf(bv, ov));
        if (ov < bv || (ov == bv && ob < bb)) { bv = ov; bb = ob; }
    }

    // lanes 0..31 hold final per-row results for this bin quarter
    if (kg == 0) {
        wres[w][col][0] = bv;
        wres[w][col][1] = b2;
        wres[w][col][2] = __int_as_float(bb);
    }
    __syncthreads();

    // final merge: threads 0..31 (wave 0) own one row each
    if (tid < 32) {
        const int row = tid;
        const float v0 = wres[0][row][0], v1 = wres[1][row][0];
        const float v2 = wres[2][row][0], v3 = wres[3][row][0];
        float fbv = v0; int fbb = __float_as_int(wres[0][row][2]);
        if (v1 < fbv) { fbv = v1; fbb = __float_as_int(wres[1][row][2]); }
        if (v2 < fbv) { fbv = v2; fbb = __float_as_int(wres[2][row][2]); }
        if (v3 < fbv) { fbv = v3; fbb = __float_as_int(wres[3][row][2]); }
        const float m01 = fminf(v0, v1), M01 = fmaxf(v0, v1);
        const float m23 = fminf(v2, v3), M23 = fmaxf(v2, v3);
        const float sec = fminf(fmaxf(m01, m23), fminf(M01, M23));
        const float fb2 = fminf(sec,
            fminf(fminf(wres[0][row][1], wres[1][row][1]),
                  fminf(wres[2][row][1], wres[3][row][1])));

        out[r0 + row] = (float)fbb;
        if (fb2 - fbv < TAU) {
            int idx = atomicAdd((int*)base + SCR_COUNT, 1);
            if (idx < LISTCAP) ((int*)base + SCR_LIST)[idx] = r0 + row;
        }
        float sx = 0.f, sxx = 0.f;
        #pragma unroll
        for (int sp = 0; sp < 8; ++sp) { sx += psx[sp][row]; sxx += psxx[sp][row]; }
        const float m  = mask[r0 + row];
        const float d2 = sxx + fbv;
        float vals[5] = { m * d2, d2, m, sx, sxx };
        #pragma unroll
        for (int off = 1; off <= 16; off <<= 1)
            #pragma unroll
            for (int q = 0; q < 5; ++q) vals[q] += __shfl_xor(vals[q], off, 64);
        if (tid == 0) {
            float* partials = base + SCR_PART;
            #pragma unroll
            for (int q = 0; q < 5; ++q)
                partials[(size_t)blockIdx.x * 8 + q] = vals[q];
        }
    }
}

// ------------------------------------------------------------------ fixup ----
// Work unit = (32-row batch) x (256-bin chunk); np-f32-exact partials -> SCR_FIX.
__global__ __launch_bounds__(256) void fixup_kernel(const float* __restrict__ x,
                                                    const float* __restrict__ k,
                                                    float* __restrict__ base) {
    __shared__ float xs[32][65];
    __shared__ float sxx_s[32];
    __shared__ float redv[256];
    __shared__ int   redb[256];

    const int tid = threadIdx.x;
    const int* count    = (const int*)base + SCR_COUNT;
    const int* flaglist = (const int*)base + SCR_LIST;
    const float* kk     = base + SCR_KK;
    float* fix          = base + SCR_FIX;
    int cnt = *count;
    if (cnt > LISTCAP) cnt = LISTCAP;
    const int nb8 = ((cnt + 31) >> 5) << 3;

    const int rloc = tid & 31, part = tid >> 5;

    for (int wk = blockIdx.x; wk < nb8; wk += gridDim.x) {
        const int bi = wk >> 3, chunk = wk & 7;
        int li = bi * 32 + rloc;
        if (li >= cnt) li = bi * 32;                 // clamp (duplicate row ok)
        const int row = flaglist[li];
        const int n = row >> 13, t = row & (T_DIM - 1);
        #pragma unroll
        for (int e = 0; e < 8; ++e)
            xs[rloc][part * 8 + e] = x[((size_t)n * C_DIM + part * 8 + e) * T_DIM + t];
        __syncthreads();
        if (tid < 32) sxx_s[tid] = np_sumsq64(&xs[tid][0]);
        __syncthreads();

        float xr[64];
        #pragma unroll
        for (int c = 0; c < 64; ++c) xr[c] = xs[rloc][c];
        const float xx = sxx_s[rloc];

        float bv = __builtin_inff();
        int   bb = 0x7fffffff;
        const int bbase = chunk * 256 + part * 32;
        #pragma unroll 1
        for (int i = 0; i < 32; i += 2) {
            const int b0 = bbase + i;
            const int b1 = b0 + 1;
            const float* k0 = k + (size_t)b0 * 64;
            const float* k1 = k + (size_t)b1 * 64;
            float d0 = 0.f, d1 = 0.f;
            #pragma unroll
            for (int c = 0; c < 64; ++c) {
                d0 = fmaf(xr[c], k0[c], d0);
                d1 = fmaf(xr[c], k1[c], d1);
            }
            float s0 = __fadd_rn(__fsub_rn(xx, __fadd_rn(d0, d0)), kk[b0]);
            float s1 = __fadd_rn(__fsub_rn(xx, __fadd_rn(d1, d1)), kk[b1]);
            if (s0 < bv || (s0 == bv && b0 < bb)) { bv = s0; bb = b0; }
            if (s1 < bv || (s1 == bv && b1 < bb)) { bv = s1; bb = b1; }
        }
        redv[tid] = bv; redb[tid] = bb;
        __syncthreads();
        if (tid < 32) {
            float fv = redv[tid]; int fb = redb[tid];
            #pragma unroll
            for (int p = 1; p < 8; ++p) {
                float ov = redv[p * 32 + tid];
                int   ob = redb[p * 32 + tid];
                if (ov < fv || (ov == fv && ob < fb)) { fv = ov; fb = ob; }
            }
            const int fi = bi * 32 + tid;
            if (fi < cnt) {
                fix[(size_t)fi * 16 + chunk * 2]     = fv;
                fix[(size_t)fi * 16 + chunk * 2 + 1] = __int_as_float(fb);
            }
        }
        __syncthreads();
    }
}

// ------------------------------------------- fixmerge + finalize (fused) ----
__global__ __launch_bounds__(256) void fixmerge_kernel(float* __restrict__ out,
                                                       float* __restrict__ base) {
    const int* count    = (const int*)base + SCR_COUNT;
    const int* flaglist = (const int*)base + SCR_LIST;
    const float* fix    = base + SCR_FIX;
    const int tid = threadIdx.x;
    int cnt = *count;
    if (cnt > LISTCAP) cnt = LISTCAP;

    for (int fi = blockIdx.x * 256 + tid; fi < cnt; fi += gridDim.x * 256) {
        const float* p = fix + (size_t)fi * 16;
        float bv = p[0];
        int   bb = __float_as_int(p[1]);
        #pragma unroll
        for (int c = 1; c < 8; ++c) {
            float v = p[c * 2];
            int   b = __float_as_int(p[c * 2 + 1]);
            if (v < bv || (v == bv && b < bb)) { bv = v; bb = b; }
        }
        out[flaglist[fi]] = (float)bb;
    }

    // block 0: finalize scalars
    if (blockIdx.x == 0) {
        const float* partials = base + SCR_PART;
        double vals[5] = {0, 0, 0, 0, 0};
        for (int i = tid; i < NBLK; i += 256)
            #pragma unroll
            for (int q = 0; q < 5; ++q) vals[q] += (double)partials[(size_t)i * 8 + q];
        #pragma unroll
        for (int off = 1; off <= 32; off <<= 1)
            #pragma unroll
            for (int q = 0; q < 5; ++q) vals[q] += __shfl_xor(vals[q], off, 64);
        __shared__ double sred[4][5];
        const int wid = tid >> 6, lane = tid & 63;
        if (lane == 0)
            for (int q = 0; q < 5; ++q) sred[wid][q] = vals[q];
        __syncthreads();
        if (tid == 0) {
            double cm  = sred[0][0] + sred[1][0] + sred[2][0] + sred[3][0];
            double fs  = sred[0][1] + sred[1][1] + sred[2][1] + sred[3][1];
            double ms  = sred[0][2] + sred[1][2] + sred[2][2] + sred[3][2];
            double sx  = sred[0][3] + sred[1][3] + sred[2][3] + sred[3][3];
            double sxx = sred[0][4] + sred[1][4] + sred[2][4] + sred[3][4];
            double sz  = (double)TOTX;
            out[NT + TOTX + 0] = (float)(cm / (ms * (double)C_DIM));
            out[NT + TOTX + 1] = (float)(fs / (double)NT);
            out[NT + TOTX + 2] = (float)sqrt(fmax(0.0, (sxx - sx * sx / sz) / sz));
        }
    }
}

// --------------------------------------------------------------------- x_d ----
// Runs LAST (also overwrites the out-region scratch in the fallback path).
__global__ __launch_bounds__(256) void xd_kernel(const float* __restrict__ mask,
                                                 const float* __restrict__ k,
                                                 float* __restrict__ out) {
    const int row = blockIdx.x * 256 + threadIdx.x;
    const int n = row >> 13, t = row & (T_DIM - 1);
    const int b = (int)out[row];
    const float m = mask[row];
    const float* kr = k + (size_t)b * C_DIM;
    float* xd = out + NT;
    #pragma unroll
    for (int c = 0; c < C_DIM; ++c)
        xd[((size_t)n * C_DIM + c) * T_DIM + t] = kr[c] * m;
}

// ----------------------------------------------------------------- launch ----
extern "C" void kernel_launch(void* const* d_in, const int* in_sizes, int n_in,
                              void* d_out, int out_size, void* d_ws, size_t ws_size,
                              hipStream_t stream) {
    (void)in_sizes; (void)n_in; (void)out_size;
    const float* x    = (const float*)d_in[0];
    const float* mask = (const float*)d_in[1];
    const float* k    = (const float*)d_in[2];
    float* out = (float*)d_out;
    float* base = (ws_size >= WS_NEED_BYTES) ? (float*)d_ws : out + NT;

    kprep_kernel<<<32, 64, 0, stream>>>(k, base);
    argmin_kernel<<<NBLK, 256, 0, stream>>>(x, mask, out, base);
    fixup_kernel<<<2048, 256, 0, stream>>>(x, k, base);
    fixmerge_kernel<<<256, 256, 0, stream>>>(out, base);
    xd_kernel<<<NT / 256, 256, 0, stream>>>(mask, k, out);
}

// Round 23
// 81.846 us; speedup vs baseline: 1.1319x; 1.0274x over previous
//
#include <hip/hip_runtime.h>

#define T_DIM 8192
#define N_DIM 8
#define C_DIM 64
#define KB    2048
#define NT    (N_DIM * T_DIM)        // 65536 rows
#define TOTX  ((size_t)NT * C_DIM)   // 4194304 elements
#define NBLK  2048                   // argmin blocks (32 rows each)
#define LISTCAP 65536
#define TAU   0.045f

// Scratch offsets in FLOAT units from scratch base (d_ws if big enough,
// else out + NT; xd_kernel runs LAST and overwrites the out-region scratch).
#define SCR_COUNT 0                   // int
#define SCR_LIST  16                  // int[65536]      -> ends 65552
#define SCR_PART  65792               // float[2048][8]  -> ends 82176
#define SCR_KK    82432               // float[2048]     -> ends 84480
#define SCR_K     90112               // f16x8 k9[16][9][128] (288 KB) -> 163840
#define SCR_FIX   262144              // float[65536][16] (4 MB) -> ends 1310720
#define WS_NEED_BYTES ((size_t)1310720 * 4)

typedef _Float16 half_t;
typedef _Float16 f16x8 __attribute__((ext_vector_type(8)));
typedef float    f32x16 __attribute__((ext_vector_type(16)));

// numpy pairwise sum (n=64) of squares (np-exact, fixup path).
__device__ __forceinline__ float np_sumsq64(const float* __restrict__ a) {
    float r[8];
    #pragma unroll
    for (int j = 0; j < 8; ++j) r[j] = __fmul_rn(a[j], a[j]);
    #pragma unroll
    for (int i = 8; i < 64; i += 8)
        #pragma unroll
        for (int j = 0; j < 8; ++j)
            r[j] = __fadd_rn(r[j], __fmul_rn(a[i + j], a[i + j]));
    return __fadd_rn(__fadd_rn(__fadd_rn(r[0], r[1]), __fadd_rn(r[2], r[3])),
                     __fadd_rn(__fadd_rn(r[4], r[5]), __fadd_rn(r[6], r[7])));
}

// ------------------------------------------------------------------ k prep ----
__global__ __launch_bounds__(64) void kprep_kernel(const float* __restrict__ k,
                                                   float* __restrict__ base) {
    const int bin = blockIdx.x * 64 + threadIdx.x;    // grid 32 -> 2048
    if (bin == 0) ((int*)base)[SCR_COUNT] = 0;

    float kv[64];
    #pragma unroll
    for (int i = 0; i < 16; ++i)
        *(float4*)&kv[i * 4] = *(const float4*)(k + (size_t)bin * 64 + i * 4);

    float kn = 0.f;
    #pragma unroll
    for (int c = 0; c < 64; ++c) kn = fmaf(kv[c], kv[c], kn);
    base[SCR_KK + bin] = np_sumsq64(kv);

    f16x8* kscr = (f16x8*)(base + SCR_K);
    const int ch = bin >> 7, b127 = bin & 127;
    #pragma unroll
    for (int slot = 0; slot < 8; ++slot) {
        f16x8 h8;
        #pragma unroll
        for (int e = 0; e < 8; ++e)
            h8[e] = (half_t)(-2.f * (float)((half_t)kv[slot * 8 + e]));
        kscr[(size_t)ch * 1152 + slot * 128 + b127] = h8;
    }
    {
        half_t knh = (half_t)kn;
        half_t knl = (half_t)(kn - (float)knh);
        f16x8 k8;
        #pragma unroll
        for (int e = 0; e < 8; ++e) k8[e] = (half_t)0.f;
        k8[0] = knh; k8[1] = knl;
        kscr[(size_t)ch * 1152 + 1024 + b127] = k8;
    }
}

// ------------------------------------------------------------------ argmin ----
// Grid 2048, block = 32 rows x 4 waves: wave w owns bins [w*512,(w+1)*512).
// BINS-AS-M, 6-bit packed keys, TWO rotating reg buffers (distance-1 —
// the R20-proven low-VGPR schedule; 4-buffer variant cost occupancy).
__global__ __launch_bounds__(256, 2) void argmin_kernel(const float* __restrict__ x,
                                                        const float* __restrict__ mask,
                                                        float* __restrict__ out,
                                                        float* __restrict__ base) {
    __shared__ __align__(16) f16x8 xhi_s[256];   // [8 slots][32 rows]
    __shared__ float psx[8][32], psxx[8][32];
    __shared__ float wres[4][32][3];

    const int tid = threadIdx.x;
    const int l   = tid & 63, w = tid >> 6;
    const int col = l & 31, kg = l >> 5;
    const int r0  = blockIdx.x * 32;
    const int n   = r0 >> 13;
    const int t0  = r0 & (T_DIM - 1);

    // prologue: x load + f16-hi split + row stats (thread: row=tid&31, 1 slot)
    {
        const int row = tid & 31, slot = tid >> 5;
        float sx = 0.f, sxx = 0.f;
        f16x8 h8;
        #pragma unroll
        for (int e = 0; e < 8; ++e) {
            float v = x[((size_t)n * C_DIM + slot * 8 + e) * T_DIM + t0 + row];
            h8[e] = (half_t)v;
            sx += v; sxx = fmaf(v, v, sxx);
        }
        xhi_s[slot * 32 + row] = h8;
        psx[slot][row]  = sx;
        psxx[slot][row] = sxx;
    }
    __syncthreads();

    // x B-fragments: col = x-row, K=64 over 4 k-steps + ones frag
    f16x8 a0 = xhi_s[(0 + kg) * 32 + col];
    f16x8 a1 = xhi_s[(2 + kg) * 32 + col];
    f16x8 a2 = xhi_s[(4 + kg) * 32 + col];
    f16x8 a3 = xhi_s[(6 + kg) * 32 + col];
    f16x8 aones;
    #pragma unroll
    for (int e = 0; e < 8; ++e) aones[e] = (half_t)0.f;
    if (kg == 0) { aones[0] = (half_t)1.f; aones[1] = (half_t)1.f; }

    // per-wave k base: bins [w*512, (w+1)*512) = chunks w*4 .. w*4+3
    const f16x8* kf0 = (const f16x8*)(base + SCR_K) + (size_t)w * 4 * 1152 + col;
    const int kgo = kg * 128;

    f32x16 zacc;
    #pragma unroll
    for (int r = 0; r < 16; ++r) zacc[r] = 0.f;

    // 4 independent top-2 packed chains: chain j handles acc entries 4j..4j+3
    float bv0 = __builtin_inff(), b20 = __builtin_inff();
    float bv1 = __builtin_inff(), b21 = __builtin_inff();
    float bv2 = __builtin_inff(), b22 = __builtin_inff();
    float bv3 = __builtin_inff(), b23 = __builtin_inff();

    f16x8 bA[4], bB[4], b4A, b4B;

#define LOADT(t, BH, B4)                                            \
    {                                                               \
        const f16x8* p = kf0 + (((t) >> 2) * 1152 + ((t) & 3) * 32);\
        BH[0] = p[kgo]; BH[1] = p[kgo + 256];                       \
        BH[2] = p[kgo + 512]; BH[3] = p[kgo + 768];                 \
        B4 = p[1024];                                               \
    }

#define UPD(J, RR, CODE)                                                     \
    {                                                                        \
        float spf = __uint_as_float(                                         \
            (__float_as_uint(acc[RR]) & 0xFFFFFFC0u) | (unsigned)(CODE));    \
        float nb2;                                                           \
        asm("v_med3_f32 %0, %1, %2, %3"                                      \
            : "=v"(nb2) : "v"(spf), "v"(bv##J), "v"(b2##J));                 \
        b2##J = nb2;                                                         \
        bv##J = fminf(bv##J, spf);                                           \
    }

#define COMPT(t, BH, B4)                                                     \
    {                                                                        \
        f32x16 acc = __builtin_amdgcn_mfma_f32_32x32x16_f16(B4, aones, zacc, 0, 0, 0); \
        acc = __builtin_amdgcn_mfma_f32_32x32x16_f16(BH[0], a0, acc, 0, 0, 0); \
        acc = __builtin_amdgcn_mfma_f32_32x32x16_f16(BH[1], a1, acc, 0, 0, 0); \
        acc = __builtin_amdgcn_mfma_f32_32x32x16_f16(BH[2], a2, acc, 0, 0, 0); \
        acc = __builtin_amdgcn_mfma_f32_32x32x16_f16(BH[3], a3, acc, 0, 0, 0); \
        const int cb4 = (t) * 4;                                             \
        UPD(0, 0, cb4 + 0)  UPD(0, 1, cb4 + 1)  UPD(0, 2, cb4 + 2)  UPD(0, 3, cb4 + 3) \
        UPD(1, 4, cb4 + 0)  UPD(1, 5, cb4 + 1)  UPD(1, 6, cb4 + 2)  UPD(1, 7, cb4 + 3) \
        UPD(2, 8, cb4 + 0)  UPD(2, 9, cb4 + 1)  UPD(2, 10, cb4 + 2) UPD(2, 11, cb4 + 3) \
        UPD(3, 12, cb4 + 0) UPD(3, 13, cb4 + 1) UPD(3, 14, cb4 + 2) UPD(3, 15, cb4 + 3) \
    }

    LOADT(0, bA, b4A);
    #pragma unroll 1
    for (int t = 0; t < 14; t += 2) {
        LOADT(t + 1, bB, b4B);
        COMPT(t, bA, b4A);
        LOADT(t + 2, bA, b4A);
        COMPT(t + 1, bB, b4B);
    }
    LOADT(15, bB, b4B);
    COMPT(14, bA, b4A);
    COMPT(15, bB, b4B);
#undef LOADT
#undef COMPT
#undef UPD

    // reconstruct (value, bin) per chain:
    // bin = w*512 + (code>>2)*32 + 8*j + (code&3) + 4*kg
    const int bbase = w * 512 + 4 * kg;
    int c0, c1, c2, c3;
    {
        unsigned q;
        q = __float_as_uint(bv0) & 63u; c0 = bbase + (int)(q >> 2) * 32 + 0  + (int)(q & 3);
        q = __float_as_uint(bv1) & 63u; c1 = bbase + (int)(q >> 2) * 32 + 8  + (int)(q & 3);
        q = __float_as_uint(bv2) & 63u; c2 = bbase + (int)(q >> 2) * 32 + 16 + (int)(q & 3);
        q = __float_as_uint(bv3) & 63u; c3 = bbase + (int)(q >> 2) * 32 + 24 + (int)(q & 3);
    }

    // merge 4 chains -> (bv, b2, bb)   [top-2 merge, tie -> lower bin]
    float bv, b2; int bb;
    {
        float m01v; int m01c; float m01s;
        if (bv1 < bv0 || (bv1 == bv0 && c1 < c0)) { m01v = bv1; m01c = c1; }
        else                                      { m01v = bv0; m01c = c0; }
        m01s = fminf(fminf(b20, b21), fmaxf(bv0, bv1));
        float m23v; int m23c; float m23s;
        if (bv3 < bv2 || (bv3 == bv2 && c3 < c2)) { m23v = bv3; m23c = c3; }
        else                                      { m23v = bv2; m23c = c2; }
        m23s = fminf(fminf(b22, b23), fmaxf(bv2, bv3));
        if (m23v < m01v || (m23v == m01v && m23c < m01c)) { bv = m23v; bb = m23c; }
        else                                              { bv = m01v; bb = m01c; }
        b2 = fminf(fminf(m01s, m23s), fmaxf(m01v, m23v));
    }

    // single-stage lane^32 merge (two bin-subsets of the same x-row)
    {
        float ov = __shfl_xor(bv, 32, 64);
        float o2 = __shfl_xor(b2, 32, 64);
        int   ob = __shfl_xor(bb, 32, 64);
        b2 = fminf(fminf(b2, o2), fmaxf(bv, ov));
        if (ov < bv || (ov == bv && ob < bb)) { bv = ov; bb = ob; }
    }

    // lanes 0..31 hold final per-row results for this bin quarter
    if (kg == 0) {
        wres[w][col][0] = bv;
        wres[w][col][1] = b2;
        wres[w][col][2] = __int_as_float(bb);
    }
    __syncthreads();

    // final merge: threads 0..31 (wave 0) own one row each
    if (tid < 32) {
        const int row = tid;
        const float v0 = wres[0][row][0], v1 = wres[1][row][0];
        const float v2 = wres[2][row][0], v3 = wres[3][row][0];
        float fbv = v0; int fbb = __float_as_int(wres[0][row][2]);
        if (v1 < fbv) { fbv = v1; fbb = __float_as_int(wres[1][row][2]); }
        if (v2 < fbv) { fbv = v2; fbb = __float_as_int(wres[2][row][2]); }
        if (v3 < fbv) { fbv = v3; fbb = __float_as_int(wres[3][row][2]); }
        const float m01 = fminf(v0, v1), M01 = fmaxf(v0, v1);
        const float m23 = fminf(v2, v3), M23 = fmaxf(v2, v3);
        const float sec = fminf(fmaxf(m01, m23), fminf(M01, M23));
        const float fb2 = fminf(sec,
            fminf(fminf(wres[0][row][1], wres[1][row][1]),
                  fminf(wres[2][row][1], wres[3][row][1])));

        out[r0 + row] = (float)fbb;
        if (fb2 - fbv < TAU) {
            int idx = atomicAdd((int*)base + SCR_COUNT, 1);
            if (idx < LISTCAP) ((int*)base + SCR_LIST)[idx] = r0 + row;
        }
        float sx = 0.f, sxx = 0.f;
        #pragma unroll
        for (int sp = 0; sp < 8; ++sp) { sx += psx[sp][row]; sxx += psxx[sp][row]; }
        const float m  = mask[r0 + row];
        const float d2 = sxx + fbv;
        float vals[5] = { m * d2, d2, m, sx, sxx };
        #pragma unroll
        for (int off = 1; off <= 16; off <<= 1)
            #pragma unroll
            for (int q = 0; q < 5; ++q) vals[q] += __shfl_xor(vals[q], off, 64);
        if (tid == 0) {
            float* partials = base + SCR_PART;
            #pragma unroll
            for (int q = 0; q < 5; ++q)
                partials[(size_t)blockIdx.x * 8 + q] = vals[q];
        }
    }
}

// ------------------------------------------------------------------ fixup ----
// Work unit = (32-row batch) x (256-bin chunk); np-f32-exact partials -> SCR_FIX.
__global__ __launch_bounds__(256) void fixup_kernel(const float* __restrict__ x,
                                                    const float* __restrict__ k,
                                                    float* __restrict__ base) {
    __shared__ float xs[32][65];
    __shared__ float sxx_s[32];
    __shared__ float redv[256];
    __shared__ int   redb[256];

    const int tid = threadIdx.x;
    const int* count    = (const int*)base + SCR_COUNT;
    const int* flaglist = (const int*)base + SCR_LIST;
    const float* kk     = base + SCR_KK;
    float* fix          = base + SCR_FIX;
    int cnt = *count;
    if (cnt > LISTCAP) cnt = LISTCAP;
    const int nb8 = ((cnt + 31) >> 5) << 3;

    const int rloc = tid & 31, part = tid >> 5;

    for (int wk = blockIdx.x; wk < nb8; wk += gridDim.x) {
        const int bi = wk >> 3, chunk = wk & 7;
        int li = bi * 32 + rloc;
        if (li >= cnt) li = bi * 32;                 // clamp (duplicate row ok)
        const int row = flaglist[li];
        const int n = row >> 13, t = row & (T_DIM - 1);
        #pragma unroll
        for (int e = 0; e < 8; ++e)
            xs[rloc][part * 8 + e] = x[((size_t)n * C_DIM + part * 8 + e) * T_DIM + t];
        __syncthreads();
        if (tid < 32) sxx_s[tid] = np_sumsq64(&xs[tid][0]);
        __syncthreads();

        float xr[64];
        #pragma unroll
        for (int c = 0; c < 64; ++c) xr[c] = xs[rloc][c];
        const float xx = sxx_s[rloc];

        float bv = __builtin_inff();
        int   bb = 0x7fffffff;
        const int bbase = chunk * 256 + part * 32;
        #pragma unroll 1
        for (int i = 0; i < 32; i += 2) {
            const int b0 = bbase + i;
            const int b1 = b0 + 1;
            const float* k0 = k + (size_t)b0 * 64;
            const float* k1 = k + (size_t)b1 * 64;
            float d0 = 0.f, d1 = 0.f;
            #pragma unroll
            for (int c = 0; c < 64; ++c) {
                d0 = fmaf(xr[c], k0[c], d0);
                d1 = fmaf(xr[c], k1[c], d1);
            }
            float s0 = __fadd_rn(__fsub_rn(xx, __fadd_rn(d0, d0)), kk[b0]);
            float s1 = __fadd_rn(__fsub_rn(xx, __fadd_rn(d1, d1)), kk[b1]);
            if (s0 < bv || (s0 == bv && b0 < bb)) { bv = s0; bb = b0; }
            if (s1 < bv || (s1 == bv && b1 < bb)) { bv = s1; bb = b1; }
        }
        redv[tid] = bv; redb[tid] = bb;
        __syncthreads();
        if (tid < 32) {
            float fv = redv[tid]; int fb = redb[tid];
            #pragma unroll
            for (int p = 1; p < 8; ++p) {
                float ov = redv[p * 32 + tid];
                int   ob = redb[p * 32 + tid];
                if (ov < fv || (ov == fv && ob < fb)) { fv = ov; fb = ob; }
            }
            const int fi = bi * 32 + tid;
            if (fi < cnt) {
                fix[(size_t)fi * 16 + chunk * 2]     = fv;
                fix[(size_t)fi * 16 + chunk * 2 + 1] = __int_as_float(fb);
            }
        }
        __syncthreads();
    }
}

// ------------------------------------------- fixmerge + finalize (fused) ----
__global__ __launch_bounds__(256) void fixmerge_kernel(float* __restrict__ out,
                                                       float* __restrict__ base) {
    const int* count    = (const int*)base + SCR_COUNT;
    const int* flaglist = (const int*)base + SCR_LIST;
    const float* fix    = base + SCR_FIX;
    const int tid = threadIdx.x;
    int cnt = *count;
    if (cnt > LISTCAP) cnt = LISTCAP;

    for (int fi = blockIdx.x * 256 + tid; fi < cnt; fi += gridDim.x * 256) {
        const float* p = fix + (size_t)fi * 16;
        float bv = p[0];
        int   bb = __float_as_int(p[1]);
        #pragma unroll
        for (int c = 1; c < 8; ++c) {
            float v = p[c * 2];
            int   b = __float_as_int(p[c * 2 + 1]);
            if (v < bv || (v == bv && b < bb)) { bv = v; bb = b; }
        }
        out[flaglist[fi]] = (float)bb;
    }

    // block 0: finalize scalars
    if (blockIdx.x == 0) {
        const float* partials = base + SCR_PART;
        double vals[5] = {0, 0, 0, 0, 0};
        for (int i = tid; i < NBLK; i += 256)
            #pragma unroll
            for (int q = 0; q < 5; ++q) vals[q] += (double)partials[(size_t)i * 8 + q];
        #pragma unroll
        for (int off = 1; off <= 32; off <<= 1)
            #pragma unroll
            for (int q = 0; q < 5; ++q) vals[q] += __shfl_xor(vals[q], off, 64);
        __shared__ double sred[4][5];
        const int wid = tid >> 6, lane = tid & 63;
        if (lane == 0)
            for (int q = 0; q < 5; ++q) sred[wid][q] = vals[q];
        __syncthreads();
        if (tid == 0) {
            double cm  = sred[0][0] + sred[1][0] + sred[2][0] + sred[3][0];
            double fs  = sred[0][1] + sred[1][1] + sred[2][1] + sred[3][1];
            double ms  = sred[0][2] + sred[1][2] + sred[2][2] + sred[3][2];
            double sx  = sred[0][3] + sred[1][3] + sred[2][3] + sred[3][3];
            double sxx = sred[0][4] + sred[1][4] + sred[2][4] + sred[3][4];
            double sz  = (double)TOTX;
            out[NT + TOTX + 0] = (float)(cm / (ms * (double)C_DIM));
            out[NT + TOTX + 1] = (float)(fs / (double)NT);
            out[NT + TOTX + 2] = (float)sqrt(fmax(0.0, (sxx - sx * sx / sz) / sz));
        }
    }
}

// --------------------------------------------------------------------- x_d ----
// Runs LAST (also overwrites the out-region scratch in the fallback path).
__global__ __launch_bounds__(256) void xd_kernel(const float* __restrict__ mask,
                                                 const float* __restrict__ k,
                                                 float* __restrict__ out) {
    const int row = blockIdx.x * 256 + threadIdx.x;
    const int n = row >> 13, t = row & (T_DIM - 1);
    const int b = (int)out[row];
    const float m = mask[row];
    const float* kr = k + (size_t)b * C_DIM;
    float* xd = out + NT;
    #pragma unroll
    for (int c = 0; c < C_DIM; ++c)
        xd[((size_t)n * C_DIM + c) * T_DIM + t] = kr[c] * m;
}

// ----------------------------------------------------------------- launch ----
extern "C" void kernel_launch(void* const* d_in, const int* in_sizes, int n_in,
                              void* d_out, int out_size, void* d_ws, size_t ws_size,
                              hipStream_t stream) {
    (void)in_sizes; (void)n_in; (void)out_size;
    const float* x    = (const float*)d_in[0];
    const float* mask = (const float*)d_in[1];
    const float* k    = (const float*)d_in[2];
    float* out = (float*)d_out;
    float* base = (ws_size >= WS_NEED_BYTES) ? (float*)d_ws : out + NT;

    kprep_kernel<<<32, 64, 0, stream>>>(k, base);
    argmin_kernel<<<NBLK, 256, 0, stream>>>(x, mask, out, base);
    fixup_kernel<<<2048, 256, 0, stream>>>(x, k, base);
    fixmerge_kernel<<<256, 256, 0, stream>>>(out, base);
    xd_kernel<<<NT / 256, 256, 0, stream>>>(mask, k, out);
}

// Round 24
// 77.991 us; speedup vs baseline: 1.1878x; 1.0494x over previous
//
#include <hip/hip_runtime.h>

#define T_DIM 8192
#define N_DIM 8
#define C_DIM 64
#define KB    2048
#define NT    (N_DIM * T_DIM)        // 65536 rows
#define TOTX  ((size_t)NT * C_DIM)   // 4194304 elements
#define NBLK  1024                   // argmin blocks (64 rows each)
#define LISTCAP 65536
#define TAU   0.045f

// Scratch offsets in FLOAT units from scratch base (d_ws if big enough,
// else out + NT; xd_kernel runs LAST and overwrites the out-region scratch).
#define SCR_COUNT 0                   // int
#define SCR_LIST  16                  // int[65536]      -> ends 65552
#define SCR_PART  65792               // float[1024][8]  -> ends 73984
#define SCR_KK    82432               // float[2048]     -> ends 84480
#define SCR_K     90112               // f16x8 k9[16][9][128] (288 KB) -> 163840
#define SCR_FIX   262144              // float[65536][16] (4 MB) -> ends 1310720
#define WS_NEED_BYTES ((size_t)1310720 * 4)

typedef _Float16 half_t;
typedef _Float16 f16x8 __attribute__((ext_vector_type(8)));
typedef float    f32x16 __attribute__((ext_vector_type(16)));

// numpy pairwise sum (n=64) of squares (np-exact, fixup path).
__device__ __forceinline__ float np_sumsq64(const float* __restrict__ a) {
    float r[8];
    #pragma unroll
    for (int j = 0; j < 8; ++j) r[j] = __fmul_rn(a[j], a[j]);
    #pragma unroll
    for (int i = 8; i < 64; i += 8)
        #pragma unroll
        for (int j = 0; j < 8; ++j)
            r[j] = __fadd_rn(r[j], __fmul_rn(a[i + j], a[i + j]));
    return __fadd_rn(__fadd_rn(__fadd_rn(r[0], r[1]), __fadd_rn(r[2], r[3])),
                     __fadd_rn(__fadd_rn(r[4], r[5]), __fadd_rn(r[6], r[7])));
}

// ------------------------------------------------------------------ k prep ----
__global__ __launch_bounds__(64) void kprep_kernel(const float* __restrict__ k,
                                                   float* __restrict__ base) {
    const int bin = blockIdx.x * 64 + threadIdx.x;    // grid 32 -> 2048
    if (bin == 0) ((int*)base)[SCR_COUNT] = 0;

    float kv[64];
    #pragma unroll
    for (int i = 0; i < 16; ++i)
        *(float4*)&kv[i * 4] = *(const float4*)(k + (size_t)bin * 64 + i * 4);

    float kn = 0.f;
    #pragma unroll
    for (int c = 0; c < 64; ++c) kn = fmaf(kv[c], kv[c], kn);
    base[SCR_KK + bin] = np_sumsq64(kv);

    f16x8* kscr = (f16x8*)(base + SCR_K);
    const int ch = bin >> 7, b127 = bin & 127;
    #pragma unroll
    for (int slot = 0; slot < 8; ++slot) {
        f16x8 h8;
        #pragma unroll
        for (int e = 0; e < 8; ++e)
            h8[e] = (half_t)(-2.f * (float)((half_t)kv[slot * 8 + e]));
        kscr[(size_t)ch * 1152 + slot * 128 + b127] = h8;
    }
    {
        half_t knh = (half_t)kn;
        half_t knl = (half_t)(kn - (float)knh);
        f16x8 k8;
        #pragma unroll
        for (int e = 0; e < 8; ++e) k8[e] = (half_t)0.f;
        k8[0] = knh; k8[1] = knl;
        kscr[(size_t)ch * 1152 + 1024 + b127] = k8;
    }
}

// ------------------------------------------------------------------ argmin ----
// Grid 1024, block = 64 rows x 4 waves: wave w owns bins [w*512,(w+1)*512)
// for ALL 64 rows (two 32-row MFMA B-sets share each k-fragment load —
// halves k L2 traffic per row). BINS-AS-M, 6-bit packed keys, 3-op UPD.
__global__ __launch_bounds__(256, 2) void argmin_kernel(const float* __restrict__ x,
                                                        const float* __restrict__ mask,
                                                        float* __restrict__ out,
                                                        float* __restrict__ base) {
    __shared__ __align__(16) f16x8 xhi_s[512];   // [8 slots][64 rows]
    __shared__ float psx[4][64], psxx[4][64];
    __shared__ float wres[4][64][3];

    const int tid = threadIdx.x;
    const int l   = tid & 63, w = tid >> 6;
    const int col = l & 31, kg = l >> 5;
    const int r0  = blockIdx.x * 64;
    const int n   = r0 >> 13;
    const int t0  = r0 & (T_DIM - 1);

    // prologue: x load + f16-hi split + row stats (thread: row=tid&63, 2 slots)
    {
        const int row = tid & 63, sp = tid >> 6;
        float sx = 0.f, sxx = 0.f;
        #pragma unroll
        for (int ss = 0; ss < 2; ++ss) {
            const int slot = sp * 2 + ss;
            f16x8 h8;
            #pragma unroll
            for (int e = 0; e < 8; ++e) {
                float v = x[((size_t)n * C_DIM + slot * 8 + e) * T_DIM + t0 + row];
                h8[e] = (half_t)v;
                sx += v; sxx = fmaf(v, v, sxx);
            }
            xhi_s[slot * 64 + row] = h8;
        }
        psx[sp][row]  = sx;
        psxx[sp][row] = sxx;
    }
    __syncthreads();

    // x B-fragments for BOTH 32-row sets (L: rows 0-31, H: rows 32-63)
    f16x8 aL0 = xhi_s[(0 + kg) * 64 + col];
    f16x8 aL1 = xhi_s[(2 + kg) * 64 + col];
    f16x8 aL2 = xhi_s[(4 + kg) * 64 + col];
    f16x8 aL3 = xhi_s[(6 + kg) * 64 + col];
    f16x8 aH0 = xhi_s[(0 + kg) * 64 + 32 + col];
    f16x8 aH1 = xhi_s[(2 + kg) * 64 + 32 + col];
    f16x8 aH2 = xhi_s[(4 + kg) * 64 + 32 + col];
    f16x8 aH3 = xhi_s[(6 + kg) * 64 + 32 + col];
    f16x8 aones;
    #pragma unroll
    for (int e = 0; e < 8; ++e) aones[e] = (half_t)0.f;
    if (kg == 0) { aones[0] = (half_t)1.f; aones[1] = (half_t)1.f; }

    // per-wave k base: bins [w*512, (w+1)*512) = chunks w*4 .. w*4+3
    const f16x8* kf0 = (const f16x8*)(base + SCR_K) + (size_t)w * 4 * 1152 + col;
    const int kgo = kg * 128;

    f32x16 zacc;
    #pragma unroll
    for (int r = 0; r < 16; ++r) zacc[r] = 0.f;

    // top-2 packed chains: 4 per row-set
    float bvL0 = __builtin_inff(), b2L0 = __builtin_inff();
    float bvL1 = __builtin_inff(), b2L1 = __builtin_inff();
    float bvL2 = __builtin_inff(), b2L2 = __builtin_inff();
    float bvL3 = __builtin_inff(), b2L3 = __builtin_inff();
    float bvH0 = __builtin_inff(), b2H0 = __builtin_inff();
    float bvH1 = __builtin_inff(), b2H1 = __builtin_inff();
    float bvH2 = __builtin_inff(), b2H2 = __builtin_inff();
    float bvH3 = __builtin_inff(), b2H3 = __builtin_inff();

    f16x8 bA[4], bB[4], b4A, b4B;

#define LOADT(t, BH, B4)                                            \
    {                                                               \
        const f16x8* p = kf0 + (((t) >> 2) * 1152 + ((t) & 3) * 32);\
        BH[0] = p[kgo]; BH[1] = p[kgo + 256];                       \
        BH[2] = p[kgo + 512]; BH[3] = p[kgo + 768];                 \
        B4 = p[1024];                                               \
    }

#define UPD(S, J, RR, CODE)                                                  \
    {                                                                        \
        float spf = __uint_as_float(                                         \
            (__float_as_uint(acc[RR]) & 0xFFFFFFC0u) | (unsigned)(CODE));    \
        float nb2;                                                           \
        asm("v_med3_f32 %0, %1, %2, %3"                                      \
            : "=v"(nb2) : "v"(spf), "v"(bv##S##J), "v"(b2##S##J));           \
        b2##S##J = nb2;                                                      \
        bv##S##J = fminf(bv##S##J, spf);                                     \
    }

#define COMPS(S, A0, A1, A2, A3, t, BH, B4)                                  \
    {                                                                        \
        f32x16 acc = __builtin_amdgcn_mfma_f32_32x32x16_f16(B4, aones, zacc, 0, 0, 0); \
        acc = __builtin_amdgcn_mfma_f32_32x32x16_f16(BH[0], A0, acc, 0, 0, 0); \
        acc = __builtin_amdgcn_mfma_f32_32x32x16_f16(BH[1], A1, acc, 0, 0, 0); \
        acc = __builtin_amdgcn_mfma_f32_32x32x16_f16(BH[2], A2, acc, 0, 0, 0); \
        acc = __builtin_amdgcn_mfma_f32_32x32x16_f16(BH[3], A3, acc, 0, 0, 0); \
        const int cb4 = (t) * 4;                                             \
        UPD(S, 0, 0, cb4 + 0)  UPD(S, 0, 1, cb4 + 1)  UPD(S, 0, 2, cb4 + 2)  UPD(S, 0, 3, cb4 + 3) \
        UPD(S, 1, 4, cb4 + 0)  UPD(S, 1, 5, cb4 + 1)  UPD(S, 1, 6, cb4 + 2)  UPD(S, 1, 7, cb4 + 3) \
        UPD(S, 2, 8, cb4 + 0)  UPD(S, 2, 9, cb4 + 1)  UPD(S, 2, 10, cb4 + 2) UPD(S, 2, 11, cb4 + 3) \
        UPD(S, 3, 12, cb4 + 0) UPD(S, 3, 13, cb4 + 1) UPD(S, 3, 14, cb4 + 2) UPD(S, 3, 15, cb4 + 3) \
    }

#define COMPT(t, BH, B4)                                                     \
    COMPS(L, aL0, aL1, aL2, aL3, t, BH, B4)                                  \
    COMPS(H, aH0, aH1, aH2, aH3, t, BH, B4)

    LOADT(0, bA, b4A);
    #pragma unroll 1
    for (int t = 0; t < 14; t += 2) {
        LOADT(t + 1, bB, b4B);
        COMPT(t, bA, b4A);
        LOADT(t + 2, bA, b4A);
        COMPT(t + 1, bB, b4B);
    }
    LOADT(15, bB, b4B);
    COMPT(14, bA, b4A);
    COMPT(15, bB, b4B);
#undef LOADT
#undef COMPT
#undef COMPS
#undef UPD

    // reconstruct + merge per row-set, then lane^32 merge, then stash
    const int bbase = w * 512 + 4 * kg;
    #pragma unroll
    for (int s = 0; s < 2; ++s) {
        float v0 = s ? bvH0 : bvL0, s0 = s ? b2H0 : b2L0;
        float v1 = s ? bvH1 : bvL1, s1 = s ? b2H1 : b2L1;
        float v2 = s ? bvH2 : bvL2, s2 = s ? b2H2 : b2L2;
        float v3 = s ? bvH3 : bvL3, s3 = s ? b2H3 : b2L3;
        unsigned q;
        int c0, c1, c2, c3;
        q = __float_as_uint(v0) & 63u; c0 = bbase + (int)(q >> 2) * 32 + 0  + (int)(q & 3);
        q = __float_as_uint(v1) & 63u; c1 = bbase + (int)(q >> 2) * 32 + 8  + (int)(q & 3);
        q = __float_as_uint(v2) & 63u; c2 = bbase + (int)(q >> 2) * 32 + 16 + (int)(q & 3);
        q = __float_as_uint(v3) & 63u; c3 = bbase + (int)(q >> 2) * 32 + 24 + (int)(q & 3);

        float bv, b2; int bb;
        {
            float m01v; int m01c; float m01s;
            if (v1 < v0 || (v1 == v0 && c1 < c0)) { m01v = v1; m01c = c1; }
            else                                  { m01v = v0; m01c = c0; }
            m01s = fminf(fminf(s0, s1), fmaxf(v0, v1));
            float m23v; int m23c; float m23s;
            if (v3 < v2 || (v3 == v2 && c3 < c2)) { m23v = v3; m23c = c3; }
            else                                  { m23v = v2; m23c = c2; }
            m23s = fminf(fminf(s2, s3), fmaxf(v2, v3));
            if (m23v < m01v || (m23v == m01v && m23c < m01c)) { bv = m23v; bb = m23c; }
            else                                              { bv = m01v; bb = m01c; }
            b2 = fminf(fminf(m01s, m23s), fmaxf(m01v, m23v));
        }
        {
            float ov = __shfl_xor(bv, 32, 64);
            float o2 = __shfl_xor(b2, 32, 64);
            int   ob = __shfl_xor(bb, 32, 64);
            b2 = fminf(fminf(b2, o2), fmaxf(bv, ov));
            if (ov < bv || (ov == bv && ob < bb)) { bv = ov; bb = ob; }
        }
        if (kg == 0) {
            wres[w][s * 32 + col][0] = bv;
            wres[w][s * 32 + col][1] = b2;
            wres[w][s * 32 + col][2] = __int_as_float(bb);
        }
    }
    __syncthreads();

    // final merge: threads 0..63 (wave 0) own one row each
    if (tid < 64) {
        const int row = tid;
        const float v0 = wres[0][row][0], v1 = wres[1][row][0];
        const float v2 = wres[2][row][0], v3 = wres[3][row][0];
        float fbv = v0; int fbb = __float_as_int(wres[0][row][2]);
        if (v1 < fbv) { fbv = v1; fbb = __float_as_int(wres[1][row][2]); }
        if (v2 < fbv) { fbv = v2; fbb = __float_as_int(wres[2][row][2]); }
        if (v3 < fbv) { fbv = v3; fbb = __float_as_int(wres[3][row][2]); }
        const float m01 = fminf(v0, v1), M01 = fmaxf(v0, v1);
        const float m23 = fminf(v2, v3), M23 = fmaxf(v2, v3);
        const float sec = fminf(fmaxf(m01, m23), fminf(M01, M23));
        const float fb2 = fminf(sec,
            fminf(fminf(wres[0][row][1], wres[1][row][1]),
                  fminf(wres[2][row][1], wres[3][row][1])));

        out[r0 + row] = (float)fbb;
        if (fb2 - fbv < TAU) {
            int idx = atomicAdd((int*)base + SCR_COUNT, 1);
            if (idx < LISTCAP) ((int*)base + SCR_LIST)[idx] = r0 + row;
        }
        float sx = 0.f, sxx = 0.f;
        #pragma unroll
        for (int sp = 0; sp < 4; ++sp) { sx += psx[sp][row]; sxx += psxx[sp][row]; }
        const float m  = mask[r0 + row];
        const float d2 = sxx + fbv;
        float vals[5] = { m * d2, d2, m, sx, sxx };
        #pragma unroll
        for (int off = 1; off <= 32; off <<= 1)
            #pragma unroll
            for (int q = 0; q < 5; ++q) vals[q] += __shfl_xor(vals[q], off, 64);
        if (tid == 0) {
            float* partials = base + SCR_PART;
            #pragma unroll
            for (int q = 0; q < 5; ++q)
                partials[(size_t)blockIdx.x * 8 + q] = vals[q];
        }
    }
}

// ------------------------------------------------------------------ fixup ----
// Work unit = (32-row batch) x (256-bin chunk); np-f32-exact partials -> SCR_FIX.
__global__ __launch_bounds__(256) void fixup_kernel(const float* __restrict__ x,
                                                    const float* __restrict__ k,
                                                    float* __restrict__ base) {
    __shared__ float xs[32][65];
    __shared__ float sxx_s[32];
    __shared__ float redv[256];
    __shared__ int   redb[256];

    const int tid = threadIdx.x;
    const int* count    = (const int*)base + SCR_COUNT;
    const int* flaglist = (const int*)base + SCR_LIST;
    const float* kk     = base + SCR_KK;
    float* fix          = base + SCR_FIX;
    int cnt = *count;
    if (cnt > LISTCAP) cnt = LISTCAP;
    const int nb8 = ((cnt + 31) >> 5) << 3;

    const int rloc = tid & 31, part = tid >> 5;

    for (int wk = blockIdx.x; wk < nb8; wk += gridDim.x) {
        const int bi = wk >> 3, chunk = wk & 7;
        int li = bi * 32 + rloc;
        if (li >= cnt) li = bi * 32;                 // clamp (duplicate row ok)
        const int row = flaglist[li];
        const int n = row >> 13, t = row & (T_DIM - 1);
        #pragma unroll
        for (int e = 0; e < 8; ++e)
            xs[rloc][part * 8 + e] = x[((size_t)n * C_DIM + part * 8 + e) * T_DIM + t];
        __syncthreads();
        if (tid < 32) sxx_s[tid] = np_sumsq64(&xs[tid][0]);
        __syncthreads();

        float xr[64];
        #pragma unroll
        for (int c = 0; c < 64; ++c) xr[c] = xs[rloc][c];
        const float xx = sxx_s[rloc];

        float bv = __builtin_inff();
        int   bb = 0x7fffffff;
        const int bbase = chunk * 256 + part * 32;
        #pragma unroll 1
        for (int i = 0; i < 32; i += 2) {
            const int b0 = bbase + i;
            const int b1 = b0 + 1;
            const float* k0 = k + (size_t)b0 * 64;
            const float* k1 = k + (size_t)b1 * 64;
            float d0 = 0.f, d1 = 0.f;
            #pragma unroll
            for (int c = 0; c < 64; ++c) {
                d0 = fmaf(xr[c], k0[c], d0);
                d1 = fmaf(xr[c], k1[c], d1);
            }
            float s0 = __fadd_rn(__fsub_rn(xx, __fadd_rn(d0, d0)), kk[b0]);
            float s1 = __fadd_rn(__fsub_rn(xx, __fadd_rn(d1, d1)), kk[b1]);
            if (s0 < bv || (s0 == bv && b0 < bb)) { bv = s0; bb = b0; }
            if (s1 < bv || (s1 == bv && b1 < bb)) { bv = s1; bb = b1; }
        }
        redv[tid] = bv; redb[tid] = bb;
        __syncthreads();
        if (tid < 32) {
            float fv = redv[tid]; int fb = redb[tid];
            #pragma unroll
            for (int p = 1; p < 8; ++p) {
                float ov = redv[p * 32 + tid];
                int   ob = redb[p * 32 + tid];
                if (ov < fv || (ov == fv && ob < fb)) { fv = ov; fb = ob; }
            }
            const int fi = bi * 32 + tid;
            if (fi < cnt) {
                fix[(size_t)fi * 16 + chunk * 2]     = fv;
                fix[(size_t)fi * 16 + chunk * 2 + 1] = __int_as_float(fb);
            }
        }
        __syncthreads();
    }
}

// ------------------------------------------- fixmerge + finalize (fused) ----
__global__ __launch_bounds__(256) void fixmerge_kernel(float* __restrict__ out,
                                                       float* __restrict__ base) {
    const int* count    = (const int*)base + SCR_COUNT;
    const int* flaglist = (const int*)base + SCR_LIST;
    const float* fix    = base + SCR_FIX;
    const int tid = threadIdx.x;
    int cnt = *count;
    if (cnt > LISTCAP) cnt = LISTCAP;

    for (int fi = blockIdx.x * 256 + tid; fi < cnt; fi += gridDim.x * 256) {
        const float* p = fix + (size_t)fi * 16;
        float bv = p[0];
        int   bb = __float_as_int(p[1]);
        #pragma unroll
        for (int c = 1; c < 8; ++c) {
            float v = p[c * 2];
            int   b = __float_as_int(p[c * 2 + 1]);
            if (v < bv || (v == bv && b < bb)) { bv = v; bb = b; }
        }
        out[flaglist[fi]] = (float)bb;
    }

    // block 0: finalize scalars
    if (blockIdx.x == 0) {
        const float* partials = base + SCR_PART;
        double vals[5] = {0, 0, 0, 0, 0};
        for (int i = tid; i < NBLK; i += 256)
            #pragma unroll
            for (int q = 0; q < 5; ++q) vals[q] += (double)partials[(size_t)i * 8 + q];
        #pragma unroll
        for (int off = 1; off <= 32; off <<= 1)
            #pragma unroll
            for (int q = 0; q < 5; ++q) vals[q] += __shfl_xor(vals[q], off, 64);
        __shared__ double sred[4][5];
        const int wid = tid >> 6, lane = tid & 63;
        if (lane == 0)
            for (int q = 0; q < 5; ++q) sred[wid][q] = vals[q];
        __syncthreads();
        if (tid == 0) {
            double cm  = sred[0][0] + sred[1][0] + sred[2][0] + sred[3][0];
            double fs  = sred[0][1] + sred[1][1] + sred[2][1] + sred[3][1];
            double ms  = sred[0][2] + sred[1][2] + sred[2][2] + sred[3][2];
            double sx  = sred[0][3] + sred[1][3] + sred[2][3] + sred[3][3];
            double sxx = sred[0][4] + sred[1][4] + sred[2][4] + sred[3][4];
            double sz  = (double)TOTX;
            out[NT + TOTX + 0] = (float)(cm / (ms * (double)C_DIM));
            out[NT + TOTX + 1] = (float)(fs / (double)NT);
            out[NT + TOTX + 2] = (float)sqrt(fmax(0.0, (sxx - sx * sx / sz) / sz));
        }
    }
}

// --------------------------------------------------------------------- x_d ----
// Runs LAST (also overwrites the out-region scratch in the fallback path).
__global__ __launch_bounds__(256) void xd_kernel(const float* __restrict__ mask,
                                                 const float* __restrict__ k,
                                                 float* __restrict__ out) {
    const int row = blockIdx.x * 256 + threadIdx.x;
    const int n = row >> 13, t = row & (T_DIM - 1);
    const int b = (int)out[row];
    const float m = mask[row];
    const float* kr = k + (size_t)b * C_DIM;
    float* xd = out + NT;
    #pragma unroll
    for (int c = 0; c < C_DIM; ++c)
        xd[((size_t)n * C_DIM + c) * T_DIM + t] = kr[c] * m;
}

// ----------------------------------------------------------------- launch ----
extern "C" void kernel_launch(void* const* d_in, const int* in_sizes, int n_in,
                              void* d_out, int out_size, void* d_ws, size_t ws_size,
                              hipStream_t stream) {
    (void)in_sizes; (void)n_in; (void)out_size;
    const float* x    = (const float*)d_in[0];
    const float* mask = (const float*)d_in[1];
    const float* k    = (const float*)d_in[2];
    float* out = (float*)d_out;
    float* base = (ws_size >= WS_NEED_BYTES) ? (float*)d_ws : out + NT;

    kprep_kernel<<<32, 64, 0, stream>>>(k, base);
    argmin_kernel<<<NBLK, 256, 0, stream>>>(x, mask, out, base);
    fixup_kernel<<<2048, 256, 0, stream>>>(x, k, base);
    fixmerge_kernel<<<256, 256, 0, stream>>>(out, base);
    xd_kernel<<<NT / 256, 256, 0, stream>>>(mask, k, out);
}